// Round 10
// baseline (96.520 us; speedup 1.0000x reference)
//
#include <hip/hip_runtime.h>
#include <climits>

#define NPTS 1024
#define DIMD 64
#define KNN  16
#define HID  256
#define EMBH 64

typedef short short8 __attribute__((ext_vector_type(8)));
typedef float f32x4  __attribute__((ext_vector_type(4)));

__device__ __forceinline__ short f2bf(float x) {            // RNE fp32->bf16
    unsigned u = __float_as_uint(x);
    unsigned r = (u + 0x7fffu + ((u >> 16) & 1u)) >> 16;
    return (short)r;
}
__device__ __forceinline__ float bf2f(short s) {
    return __uint_as_float(((unsigned)(unsigned short)s) << 16);
}

// A-operand LDS layout (shorts): element (k, m) of A[16 m][K k]
#define AOFF(k, m) ((((k) >> 3) * 16 + (m)) * 8 + ((k) & 7))

// ws layout (shorts) — B-fragment bf16 planes
#define A1H 0
#define A2H 16384
#define WKH 32768
#define WVH 36864
#define P2H 40960

// ---------- prep: vectorized weight -> B-fragment bf16 conversion ----------
// thread e -> (frag f, lane): writes 8 contiguous shorts (one short8 store).
__global__ __launch_bounds__(256) void prep_weights(
    const float* __restrict__ A1, const float* __restrict__ A2,
    const float* __restrict__ Wk, const float* __restrict__ Wv,
    const float* __restrict__ P2, short* __restrict__ ws)
{
    int e = blockIdx.x * 256 + threadIdx.x;   // 0 .. 88*64-1
    if (e >= 88 * 64) return;
    int f = e >> 6, lane = e & 63;
    int q = (lane >> 4) & 3, nn = lane & 15;
    const float* src; int N, base, lf, cpt;
    if (f < 32)      { src = A1; N = 256; base = A1H; lf = f;      cpt = 2; }
    else if (f < 64) { src = A2; N = 64;  base = A2H; lf = f - 32; cpt = 8; }
    else if (f < 72) { src = Wk; N = 64;  base = WKH; lf = f - 64; cpt = 2; }
    else if (f < 80) { src = Wv; N = 64;  base = WVH; lf = f - 72; cpt = 2; }
    else             { src = P2; N = 64;  base = P2H; lf = f - 80; cpt = 2; }
    int T = lf / cpt, c = lf % cpt;
    int n  = T * 16 + nn;
    int k0 = c * 32 + q * 8;
    short8 v;
    #pragma unroll
    for (int j = 0; j < 8; j++) v[j] = f2bf(src[(k0 + j) * N + n]);
    *(short8*)(ws + base + lf * 512 + lane * 8) = v;
}

// ---------- per-point LDS layout (byte offsets within a point's region) ----------
// shorts:  XN_HI 0 | XN_LO 1024 | ES_HI 2048 | ES_LO 3072 | H_HI 4096 | H_LO 5120
//          HD_HI 0 (overlays XN/ES, dead after Group1) | HD_LO 6144
// ints:    HIST 3072 (2x257, inside HD_LO region, dead before StepC)
//          TIE 2048 (inside H region, dead before Group1)
//          IDX 7360 | CTRL 7376 (cnt,cnt2,need,pref)
// floats:  VG 5120 | SIM 6208 | Q 7296
#define PT_STRIDE 29568
#define S_XN_HI 0
#define S_XN_LO 1024
#define S_ES_HI 2048
#define S_ES_LO 3072
#define S_H_HI  4096
#define S_H_LO  5120
#define S_HD_HI 0
#define S_HD_LO 6144
#define I_HIST  3072
#define I_TIE   2048
#define I_IDX   7360
#define I_CTRL  7376
#define F_VG    5120
#define F_SIM   6208
#define F_Q     7296

// ---------- main fused kernel: one block (256 thr) per TWO points ----------
__global__ __launch_bounds__(256, 4) void ptl_fused(
    const float* __restrict__ x,  const float* __restrict__ pos,
    const float* __restrict__ Wq,
    const float* __restrict__ P1, const float* __restrict__ pb1,
    const float* __restrict__ pb2,
    const float* __restrict__ ab1, const float* __restrict__ ab2,
    const short* __restrict__ ws,
    float* __restrict__ out)
{
    __shared__ __align__(16) char smem[2 * PT_STRIDE];

    const int tid  = threadIdx.x;
    const int lane = tid & 63;
    const int w    = tid >> 6;        // wave 0..3
    const int h    = w & 1;           // half within point
    const int p    = tid >> 7;        // point 0/1
    const int tl   = tid & 127;       // thread-in-point
    const int q4   = lane >> 4;
    const int col  = lane & 15;

    char* bptr = smem + p * PT_STRIDE;
    short* sS = (short*)bptr;
    float* sF = (float*)bptr;
    int*   sI = (int*)bptr;

    const int ip = blockIdx.x * 2 + p;
    const float px = pos[ip*3+0], py = pos[ip*3+1], pz = pos[ip*3+2];

    // ---- Phase 1: 1024 distance keys per point (non-fused fp32 = np's key) ----
    unsigned ku[8];
    #pragma unroll
    for (int u = 0; u < 8; u++) {
        int j = tl + 128 * u;
        float dx = __fsub_rn(px, pos[j*3+0]);
        float dy = __fsub_rn(py, pos[j*3+1]);
        float dz = __fsub_rn(pz, pos[j*3+2]);
        float s  = __fadd_rn(__fadd_rn(__fmul_rn(dx,dx), __fmul_rn(dy,dy)), __fmul_rn(dz,dz));
        ku[u] = __float_as_uint(__fsqrt_rn(s));
    }

    // ---- Phase 2: exact MSB radix-select of 16 smallest (per point, concurrent) ----
    int* hist = sI + I_HIST;     // 2 x 257
    int* ctrl = sI + I_CTRL;     // [cnt, cnt2, need, pref]
    if (tl == 0) { ctrl[0] = 0; ctrl[1] = 0; ctrl[2] = KNN; ctrl[3] = 0; }

    for (int r = 0; r < 4; r++) {
        const int shift = 24 - 8 * r;
        for (int t = tl; t < 2 * 257; t += 128) hist[t] = 0;
        __syncthreads();
        unsigned pref = (unsigned)ctrl[3];
        #pragma unroll
        for (int u = 0; u < 8; u++) {
            unsigned k = ku[u];
            bool match = (r == 0) || ((k >> (shift + 8)) == (pref >> (shift + 8)));
            if (match) atomicAdd(&hist[h * 257 + ((k >> shift) & 255)], 1);
        }
        __syncthreads();
        if (h == 0) {    // wave 2p scans its point's histogram
            int b0 = lane * 4, cnt4[4], loc = 0;
            #pragma unroll
            for (int t = 0; t < 4; t++) {
                int s = hist[b0 + t] + hist[257 + b0 + t];
                cnt4[t] = s; loc += s;
            }
            int incl = loc;
            #pragma unroll
            for (int off = 1; off < 64; off <<= 1) {
                int t = __shfl_up(incl, off);
                if (lane >= off) incl += t;
            }
            int excl = incl - loc;
            int need = ctrl[2];
            unsigned long long mk = __ballot(incl >= need);
            int lstar = (int)__ffsll((long long)mk) - 1;
            if (lane == lstar) {
                int run = excl, t = 0;
                while (t < 3 && run + cnt4[t] < need) { run += cnt4[t]; t++; }
                ctrl[3] = (int)(pref | ((unsigned)(b0 + t) << shift));
                ctrl[2] = need - run;
            }
        }
        __syncthreads();
    }
    const unsigned T = (unsigned)ctrl[3];
    const int needT  = ctrl[2];

    int* tie = sI + I_TIE;
    int* idx = sI + I_IDX;
    #pragma unroll
    for (int u = 0; u < 8; u++) {
        unsigned k = ku[u];
        int j = tl + 128 * u;
        if (k < T)       { int pp = atomicAdd(&ctrl[0], 1); idx[pp] = j; }
        else if (k == T) { int pp = atomicAdd(&ctrl[1], 1); if (pp < 256) tie[pp] = j; }
    }
    __syncthreads();

    if (h == 0) {        // wave 2p: merge ties (smallest indices = np stable top_k set)
        int base = ctrl[0];
        int m = ctrl[1];
        if (m == needT) {
            for (int t = lane; t < m; t += 64) idx[base + t] = tie[t];
        } else {
            int cand[4];
            #pragma unroll
            for (int t = 0; t < 4; t++) {
                int e = lane + 64 * t;
                cand[t] = (e < m && e < 256) ? tie[e] : INT_MAX;
            }
            for (int sel = 0; sel < needT; sel++) {
                int mv = cand[0];
                #pragma unroll
                for (int t = 1; t < 4; t++) mv = min(mv, cand[t]);
                #pragma unroll
                for (int off = 32; off > 0; off >>= 1) mv = min(mv, __shfl_xor(mv, off));
                #pragma unroll
                for (int t = 0; t < 4; t++) if (cand[t] == mv) cand[t] = INT_MAX;
                if (lane == 0) idx[base + sel] = mv;
            }
        }
    } else {             // wave 2p+1: q = x_ip @ Wq
        int d = lane;
        const float4* xr = (const float4*)(x + ip * DIMD);
        float aq = 0.f;
        #pragma unroll
        for (int cb = 0; cb < DIMD / 4; cb++) {
            float4 xv = xr[cb];
            const float* wq = Wq + (cb*4) * DIMD + d;
            aq = fmaf(xv.x, wq[0*DIMD], aq); aq = fmaf(xv.y, wq[1*DIMD], aq);
            aq = fmaf(xv.z, wq[2*DIMD], aq); aq = fmaf(xv.w, wq[3*DIMD], aq);
        }
        sF[F_Q + d] = aq;
    }
    __syncthreads();

    // ---- Phase 3: gather xn + emb1 as A-frag bf16 hi/lo ----
    #pragma unroll
    for (int u = 0; u < 8; u++) {
        int t = tl + 128 * u;           // 0..1023
        int kk = t >> 6, c = t & 63;
        int j = idx[kk];
        int ao = AOFF(c, kk);
        float xv = x[j * DIMD + c];
        short xh = f2bf(xv);
        sS[S_XN_HI + ao] = xh;
        sS[S_XN_LO + ao] = f2bf(xv - bf2f(xh));
        float dx = px - pos[j*3+0];
        float dy = py - pos[j*3+1];
        float dz = pz - pos[j*3+2];
        float a = pb1[c];
        a = fmaf(dx, P1[0*EMBH+c], a);
        a = fmaf(dy, P1[1*EMBH+c], a);
        a = fmaf(dz, P1[2*EMBH+c], a);
        a = fmaxf(a, 0.0f);
        short eh = f2bf(a);
        sS[S_ES_HI + ao] = eh;
        sS[S_ES_LO + ao] = f2bf(a - bf2f(eh));
    }
    __syncthreads();

    const short8* wsv = (const short8*)ws;
    auto bfrag = [&](int short_base, int f) -> short8 {
        return wsv[(short_base >> 3) + f * 64 + lane];
    };
    const short8* xnh = (const short8*)(sS + S_XN_HI);
    const short8* xnl = (const short8*)(sS + S_XN_LO);
    const short8* esh = (const short8*)(sS + S_ES_HI);
    const short8* esl = (const short8*)(sS + S_ES_LO);
    const short8* hhv = (const short8*)(sS + S_H_HI);
    const short8* hlv = (const short8*)(sS + S_H_LO);
    const short8* hdh = (const short8*)(sS + S_HD_HI);
    const short8* hdl = (const short8*)(sS + S_HD_LO);

    // ---- Group 1 MFMA: kn=xn@Wk, vn=xn@Wv, rpe=emb1@P2 (16x64, K=64); wave owns 2 col-tiles ----
    {
        short8 xh[2], xl[2], eh[2], el[2];
        #pragma unroll
        for (int c = 0; c < 2; c++) {
            int av = (4*c + q4) * 16 + col;
            xh[c] = xnh[av]; xl[c] = xnl[av];
            eh[c] = esh[av]; el[c] = esl[av];
        }
        f32x4 acck[2], accv[2], accr[2];
        #pragma unroll
        for (int T2 = 0; T2 < 2; T2++) {
            int Tt = h * 2 + T2;
            f32x4 ak = {0,0,0,0}, av_ = {0,0,0,0}, ar = {0,0,0,0};
            #pragma unroll
            for (int c = 0; c < 2; c++) {
                int f = Tt * 2 + c;
                short8 bk = bfrag(WKH, f);
                ak = __builtin_amdgcn_mfma_f32_16x16x32_bf16(xh[c], bk, ak, 0,0,0);
                ak = __builtin_amdgcn_mfma_f32_16x16x32_bf16(xl[c], bk, ak, 0,0,0);
            }
            #pragma unroll
            for (int c = 0; c < 2; c++) {
                int f = Tt * 2 + c;
                short8 bv = bfrag(WVH, f);
                av_ = __builtin_amdgcn_mfma_f32_16x16x32_bf16(xh[c], bv, av_, 0,0,0);
                av_ = __builtin_amdgcn_mfma_f32_16x16x32_bf16(xl[c], bv, av_, 0,0,0);
            }
            #pragma unroll
            for (int c = 0; c < 2; c++) {
                int f = Tt * 2 + c;
                short8 bp = bfrag(P2H, f);
                ar = __builtin_amdgcn_mfma_f32_16x16x32_bf16(eh[c], bp, ar, 0,0,0);
                ar = __builtin_amdgcn_mfma_f32_16x16x32_bf16(el[c], bp, ar, 0,0,0);
            }
            acck[T2] = ak; accv[T2] = av_; accr[T2] = ar;
        }
        #pragma unroll
        for (int T2 = 0; T2 < 2; T2++) {
            int d = (h * 2 + T2) * 16 + col;
            float qd = sF[F_Q + d], pb = pb2[d];
            #pragma unroll
            for (int r = 0; r < 4; r++) {
                int s = q4 * 4 + r;
                float rpe = accr[T2][r] + pb;
                float hv  = qd - acck[T2][r] + rpe;
                sF[F_VG + s * 68 + d] = accv[T2][r] + rpe;
                int ao = AOFF(d, s);
                short hh = f2bf(hv);
                sS[S_H_HI + ao] = hh;
                sS[S_H_LO + ao] = f2bf(hv - bf2f(hh));
            }
        }
    }
    __syncthreads();

    // ---- Step C MFMA: hidden = relu(h @ A1 + ab1), 16x256, K=64; wave owns 8 col-tiles ----
    {
        short8 hh[2], hl[2];
        #pragma unroll
        for (int c = 0; c < 2; c++) {
            int av = (4*c + q4) * 16 + col;
            hh[c] = hhv[av]; hl[c] = hlv[av];
        }
        #pragma unroll
        for (int t = 0; t < 8; t++) {
            int Tt = h * 8 + t;
            f32x4 acc = {0,0,0,0};
            #pragma unroll
            for (int c = 0; c < 2; c++) {
                short8 bh = bfrag(A1H, Tt * 2 + c);
                acc = __builtin_amdgcn_mfma_f32_16x16x32_bf16(hh[c], bh, acc, 0,0,0);
                acc = __builtin_amdgcn_mfma_f32_16x16x32_bf16(hl[c], bh, acc, 0,0,0);
            }
            int n = Tt * 16 + col;
            float bias = ab1[n];
            #pragma unroll
            for (int r = 0; r < 4; r++) {
                float val = fmaxf(acc[r] + bias, 0.0f);
                int ao = AOFF(n, q4 * 4 + r);
                short vh = f2bf(val);
                sS[S_HD_HI + ao] = vh;
                sS[S_HD_LO + ao] = f2bf(val - bf2f(vh));
            }
        }
    }
    __syncthreads();

    // ---- Step D MFMA: sim = hidden @ A2 + ab2, 16x64, K=256; wave owns 2 col-tiles ----
    #pragma unroll
    for (int T2 = 0; T2 < 2; T2++) {
        int Tt = h * 2 + T2;
        f32x4 acc = {0,0,0,0};
        #pragma unroll
        for (int c = 0; c < 8; c++) {
            int av = (4*c + q4) * 16 + col;
            short8 ah = hdh[av], al = hdl[av];
            short8 bh = bfrag(A2H, Tt * 8 + c);
            acc = __builtin_amdgcn_mfma_f32_16x16x32_bf16(ah, bh, acc, 0,0,0);
            acc = __builtin_amdgcn_mfma_f32_16x16x32_bf16(al, bh, acc, 0,0,0);
        }
        int n = Tt * 16 + col;
        float bias = ab2[n];
        #pragma unroll
        for (int r = 0; r < 4; r++)
            sF[F_SIM + (q4 * 4 + r) * 68 + n] = acc[r] + bias;
    }
    __syncthreads();

    // ---- Step E: softmax over neighbors per dim, weighted sum of vg ----
    if (tl < DIMD) {
        int d = tl;
        float mx = -3.0e38f;
        #pragma unroll
        for (int kk = 0; kk < KNN; kk++) mx = fmaxf(mx, sF[F_SIM + kk * 68 + d]);
        float den = 0.0f, num = 0.0f;
        #pragma unroll
        for (int kk = 0; kk < KNN; kk++) {
            float e = expf(sF[F_SIM + kk * 68 + d] - mx);
            den += e;
            num = fmaf(e, sF[F_VG + kk * 68 + d], num);
        }
        out[ip * DIMD + d] = num / den;
    }
}

extern "C" void kernel_launch(void* const* d_in, const int* in_sizes, int n_in,
                              void* d_out, int out_size, void* d_ws, size_t ws_size,
                              hipStream_t stream) {
    const float* x   = (const float*)d_in[0];
    const float* pos = (const float*)d_in[1];
    const float* Wq  = (const float*)d_in[2];
    const float* Wk  = (const float*)d_in[3];
    const float* Wv  = (const float*)d_in[4];
    const float* P1  = (const float*)d_in[5];
    const float* pb1 = (const float*)d_in[6];
    const float* P2  = (const float*)d_in[7];
    const float* pb2 = (const float*)d_in[8];
    const float* A1  = (const float*)d_in[9];
    const float* ab1 = (const float*)d_in[10];
    const float* A2  = (const float*)d_in[11];
    const float* ab2 = (const float*)d_in[12];
    float* out = (float*)d_out;
    short* ws  = (short*)d_ws;

    prep_weights<<<22, 256, 0, stream>>>(A1, A2, Wk, Wv, P2, ws);
    ptl_fused<<<NPTS / 2, 256, 0, stream>>>(x, pos, Wq, P1, pb1, pb2, ab1, ab2, ws, out);
}